// Round 12
// baseline (213.902 us; speedup 1.0000x reference)
//
#include <hip/hip_runtime.h>
#include <hip/hip_bf16.h>
#include <stdint.h>

#define M_DIM 8192
#define N_DIM 4096
#define K_DIM 4096

typedef int i32x4 __attribute__((ext_vector_type(4)));

#define NB_X 2048
#define NB_W 1024
#define NB_TOT (NB_X + NB_W)

// ---------------- absmax: per-block partial max, 32B/lane, no atomics ----------------
__global__ void w8a8_absmax_kernel(const float* __restrict__ x,
                                   const float* __restrict__ w,
                                   float* __restrict__ partials) {
    int b = blockIdx.x;
    const float4* p;
    int n8, bi, nb;
    if (b < NB_X) { p = (const float4*)x; n8 = (M_DIM * K_DIM) / 8; bi = b;        nb = NB_X; }
    else          { p = (const float4*)w; n8 = (N_DIM * K_DIM) / 8; bi = b - NB_X; nb = NB_W; }

    float m = 0.f;
    int stride = nb * 256;
    for (int i = bi * 256 + threadIdx.x; i < n8; i += stride) {
        float4 v0 = p[2 * i];
        float4 v1 = p[2 * i + 1];
        float m0 = fmaxf(fmaxf(fabsf(v0.x), fabsf(v0.y)), fmaxf(fabsf(v0.z), fabsf(v0.w)));
        float m1 = fmaxf(fmaxf(fabsf(v1.x), fabsf(v1.y)), fmaxf(fabsf(v1.z), fabsf(v1.w)));
        m = fmaxf(m, fmaxf(m0, m1));
    }
    #pragma unroll
    for (int o = 32; o > 0; o >>= 1)
        m = fmaxf(m, __shfl_xor(m, o, 64));

    __shared__ float red[4];
    if ((threadIdx.x & 63) == 0) red[threadIdx.x >> 6] = m;
    __syncthreads();
    if (threadIdx.x == 0)
        partials[b] = fmaxf(fmaxf(red[0], red[1]), fmaxf(red[2], red[3]));
}

// ---------------- quantize (finalize folded in): every block reduces partials itself ----------------
__global__ void w8a8_quant_kernel(const float* __restrict__ x,
                                  const float* __restrict__ w,
                                  uint2* __restrict__ qx,
                                  uint2* __restrict__ qw,
                                  const float* __restrict__ partials,
                                  float* __restrict__ finals) {
    int b = blockIdx.x;
    const float4* in4;
    uint2* outq;
    int n8, bi, nb;
    const float* pp;
    int np;
    if (b < NB_X) { in4 = (const float4*)x; outq = qx; n8 = (M_DIM * K_DIM) / 8; bi = b;        nb = NB_X; pp = partials;        np = NB_X; }
    else          { in4 = (const float4*)w; outq = qw; n8 = (N_DIM * K_DIM) / 8; bi = b - NB_X; nb = NB_W; pp = partials + NB_X; np = NB_W; }

    float m = 0.f;
    for (int i = threadIdx.x; i < np; i += 256)
        m = fmaxf(m, pp[i]);
    #pragma unroll
    for (int o = 32; o > 0; o >>= 1)
        m = fmaxf(m, __shfl_xor(m, o, 64));
    __shared__ float red[4];
    if ((threadIdx.x & 63) == 0) red[threadIdx.x >> 6] = m;
    __syncthreads();
    float am = fmaxf(fmaxf(red[0], red[1]), fmaxf(red[2], red[3]));
    float scale = fmaxf(am, 1e-5f) / 127.0f;
    if (threadIdx.x == 0 && (b == 0 || b == NB_X))
        finals[(b == 0) ? 0 : 1] = scale;

    int stride = nb * 256;
    for (int i = bi * 256 + threadIdx.x; i < n8; i += stride) {
        float4 v0 = in4[2 * i];
        float4 v1 = in4[2 * i + 1];
        int a0 = (int)rintf(v0.x / scale), a1 = (int)rintf(v0.y / scale);
        int a2 = (int)rintf(v0.z / scale), a3 = (int)rintf(v0.w / scale);
        int a4 = (int)rintf(v1.x / scale), a5 = (int)rintf(v1.y / scale);
        int a6 = (int)rintf(v1.z / scale), a7 = (int)rintf(v1.w / scale);
        uint2 o;
        o.x = (unsigned)(a0 & 0xff) | ((unsigned)(a1 & 0xff) << 8) |
              ((unsigned)(a2 & 0xff) << 16) | ((unsigned)(a3 & 0xff) << 24);
        o.y = (unsigned)(a4 & 0xff) | ((unsigned)(a5 & 0xff) << 8) |
              ((unsigned)(a6 & 0xff) << 16) | ((unsigned)(a7 & 0xff) << 24);
        outq[i] = o;
    }
}

// ========== 256x256 i8 GEMM: balanced-read pipeline (4/8/8/4 reads per phase) ==========
// 512 threads = 8 waves (2M x 4N). Per-wave C: 128x64 = acc[8][4] of i32x4. 16x16x64 MFMA.
// BK=128 i8. LDS: 2 x 64KB. Quadrant walk P1(0,0) P2(0,1) P3(1,1) P4(1,0).
// Next-tile read-ahead split: A0' in P3, B0' in P4 (OBUF validated at end of P2).
// Drain ledger (reads drained >=1 barrier before their region's re-stage):
//   A.mh0 (read prev-P3 as aA0') & B.nh0 (read prev-P4 as B0') -> drained P1 LGKM(4) -> staged P2
//   B.nh1 (read P1 bB1)                                        -> drained P2 LGKM(8) -> staged P3
//   A.mh1 (read P2 aA1)                                        -> drained P3 LGKM(8) -> staged P4
// vmcnt ledger/wave: entry 8 (prev tile's OBUF stages: 4+2+2); P2 +4 = 12; VMW(4) end-P2
// retires exactly those 8 -> BAR -> OBUF valid for P3/P4 reads; P3 +2 (6); P4 +2 -> exit 8.
// P4 needs NO lgkm wait (aA1 drained P3; B0C drained P1).
#define BM 256
#define BN 256
#define BK 128
#define NT (K_DIM / BK)      // 32 K-tiles
#define NTN (N_DIM / BN)     // 16
#define LDS_BUF 65536

#define STAGE_A(BUF, MH, KT) do {                                              \
    _Pragma("unroll")                                                          \
    for (int r_ = 0; r_ < 2; ++r_)                                             \
        __builtin_amdgcn_global_load_lds(                                      \
            (const __attribute__((address_space(1))) void*)(a_base + (size_t)((KT) + goffA[MH][r_])), \
            (__attribute__((address_space(3))) void*)(lds + (BUF)*LDS_BUF + (MH)*16384 + ldst[r_]),   \
            16, 0, 0);                                                         \
} while (0)

#define STAGE_B(BUF, NH, KT) do {                                              \
    _Pragma("unroll")                                                          \
    for (int r_ = 0; r_ < 2; ++r_)                                             \
        __builtin_amdgcn_global_load_lds(                                      \
            (const __attribute__((address_space(1))) void*)(b_base + (size_t)((KT) + goffB[NH][r_])), \
            (__attribute__((address_space(3))) void*)(lds + (BUF)*LDS_BUF + 32768 + (NH)*16384 + ldst[r_]), \
            16, 0, 0);                                                         \
} while (0)

// read A.mh frags (8 x ds_read_b128) into DST[4][2]
#define RA_A(BUF, MH, DST) do {                                                \
    _Pragma("unroll")                                                          \
    for (int m4_ = 0; m4_ < 4; ++m4_) {                                        \
        DST[m4_][0] = *(const i32x4*)(lds + (BUF)*LDS_BUF + (MH)*16384 + laneA + m4_*2048 + koff[0]); \
        DST[m4_][1] = *(const i32x4*)(lds + (BUF)*LDS_BUF + (MH)*16384 + laneA + m4_*2048 + koff[1]); \
    }                                                                          \
} while (0)

// read B.nh frags (4 x ds_read_b128) into DST[2][2]
#define RA_B(BUF, NH, DST) do {                                                \
    _Pragma("unroll")                                                          \
    for (int n1_ = 0; n1_ < 2; ++n1_) {                                        \
        DST[n1_][0] = *(const i32x4*)(lds + (BUF)*LDS_BUF + 32768 + (NH)*16384 + laneB + n1_*2048 + koff[0]); \
        DST[n1_][1] = *(const i32x4*)(lds + (BUF)*LDS_BUF + 32768 + (NH)*16384 + laneB + n1_*2048 + koff[1]); \
    }                                                                          \
} while (0)

#define MMA4(MH, NH, AARR, BARR) do {                                          \
    __builtin_amdgcn_s_setprio(1);                                             \
    _Pragma("unroll")                                                          \
    for (int m4_ = 0; m4_ < 4; ++m4_) {                                        \
        _Pragma("unroll")                                                      \
        for (int n1_ = 0; n1_ < 2; ++n1_) {                                    \
            i32x4 c_ = acc[(MH)*4 + m4_][(NH)*2 + n1_];                        \
            c_ = __builtin_amdgcn_mfma_i32_16x16x64_i8(AARR[m4_][0], BARR[n1_][0], c_, 0, 0, 0); \
            c_ = __builtin_amdgcn_mfma_i32_16x16x64_i8(AARR[m4_][1], BARR[n1_][1], c_, 0, 0, 0); \
            acc[(MH)*4 + m4_][(NH)*2 + n1_] = c_;                              \
        }                                                                      \
    }                                                                          \
    __builtin_amdgcn_s_setprio(0);                                             \
} while (0)

#define BAR() __builtin_amdgcn_s_barrier()
#define SB0() __builtin_amdgcn_sched_barrier(0)
#define VMW(N) asm volatile("s_waitcnt vmcnt(" #N ")" ::: "memory")
#define LGKM(N) asm volatile("s_waitcnt lgkmcnt(" #N ")" ::: "memory")

#define TILE_BODY(BUF, OBUF, KT2, B0C, B0N) do {                               \
    /* P1: read-ahead B1 (4); MMA(0,0) after prev P3+P4 reads drain */         \
    RA_B(BUF, 1, bB1);                                                         \
    SB0(); LGKM(4); SB0();                                                     \
    MMA4(0, 0, aA0, B0C);                                                      \
    BAR();                                                                     \
    /* P2: stage A.mh0+B.nh0 (drained P1); read-ahead A1 (8); MMA(0,1); validate OBUF */ \
    STAGE_A(BUF, 0, KT2); STAGE_B(BUF, 0, KT2);                                \
    RA_A(BUF, 1, aA1);                                                         \
    SB0(); LGKM(8); SB0();          /* B1 done */                              \
    MMA4(0, 1, aA0, bB1);                                                      \
    SB0(); VMW(4);                  /* retire prev tile's 8 OBUF stages */     \
    BAR();                          /* OBUF valid block-wide */                \
    /* P3: stage B.nh1 (drained P2); read-ahead next tile A0 from OBUF (8); MMA(1,1) */ \
    STAGE_B(BUF, 1, KT2);                                                      \
    RA_A(OBUF, 0, aA0);                                                        \
    SB0(); LGKM(8); SB0();          /* A1 done */                              \
    MMA4(1, 1, aA1, bB1);                                                      \
    BAR();                                                                     \
    /* P4: stage A.mh1 (drained P3); read-ahead next tile B0 from OBUF (4); MMA from regs */ \
    STAGE_A(BUF, 1, KT2);                                                      \
    RA_B(OBUF, 0, B0N);                                                        \
    SB0();                          /* pin read-ahead above MMA; no wait needed */ \
    MMA4(1, 0, aA1, B0C);                                                      \
    BAR();                                                                     \
} while (0)

__global__ __launch_bounds__(512, 1) void w8a8_gemm_kernel(
    const signed char* __restrict__ qa,   // [M, K]
    const signed char* __restrict__ qb,   // [N, K]
    const float* __restrict__ bias,       // [N]
    const float* __restrict__ finals,     // {scale_x, scale_w}
    float* __restrict__ out)              // [M, N]
{
    __shared__ __align__(16) char lds[2 * LDS_BUF];

    int t    = threadIdx.x;      // 0..511
    int lane = t & 63;
    int wid  = t >> 6;           // 0..7
    int wm   = wid >> 2;         // 0..1
    int wn   = wid & 3;          // 0..3
    int fr   = lane & 15;
    int fg   = lane >> 4;        // 0..3
    int frb2 = (fr >> 2) & 1;

    int bid = blockIdx.x;
    int cpx = gridDim.x >> 3;    // 64 (512 blocks % 8 == 0, bijective)
    int swz = (bid & 7) * cpx + (bid >> 3);
    int tm = swz / NTN;          // 0..31
    int tn = swz % NTN;          // 0..15

    const signed char* a_base = qa + (size_t)tm * BM * K_DIM;
    const signed char* b_base = qb + (size_t)tn * BN * K_DIM;

    // ---- staging precompute (per-thread constants across K) ----
    int goffA[2][2], goffB[2][2], ldst[2];
    #pragma unroll
    for (int r = 0; r < 2; ++r) {
        int unit = r * 512 + t;          // 0..1023
        int sl   = unit >> 3;            // 0..127
        int c    = unit & 7;
        int cs   = c ^ (sl & 7);         // inverse swizzle on global source
        int rowA = (sl & 63) + ((sl >> 6) & 1) * 128;
        goffA[0][r] = rowA * K_DIM + cs * 16;
        goffA[1][r] = (rowA + 64) * K_DIM + cs * 16;
        int rowB = ((sl >> 5) & 3) * 64 + (sl & 31);
        goffB[0][r] = rowB * K_DIM + cs * 16;
        goffB[1][r] = (rowB + 32) * K_DIM + cs * 16;
        ldst[r] = r * 8192 + t * 16;
    }

    // ---- read-side lane bases (swizzled) ----
    int laneA = (wm * 64 + fr) * 128 + (fg ^ (fr & 3)) * 16;
    int laneB = (wn * 32 + fr) * 128 + (fg ^ (fr & 3)) * 16;
    int koff[2];
    koff[0] = frb2 * 64;          // swizzled location of k-half 0
    koff[1] = 64 - frb2 * 64;     // swizzled location of k-half 1

    i32x4 acc[8][4] = {};
    i32x4 aA0[4][2], aA1[4][2], bB1[2][2], bB0a[2][2], bB0b[2][2];

    // ---- prologue: stage tile0 -> buf0, tile1 -> buf1; confirm buf0; preread P1 frags ----
    STAGE_A(0, 0, 0);  STAGE_A(0, 1, 0);  STAGE_B(0, 0, 0);  STAGE_B(0, 1, 0);
    STAGE_A(1, 0, BK); STAGE_A(1, 1, BK); STAGE_B(1, 0, BK); STAGE_B(1, 1, BK);
    VMW(8);            // retire tile0's 8; tile1's 8 in flight (= steady-state entry 8)
    BAR();             // buf0 valid block-wide
    RA_A(0, 0, aA0); RA_B(0, 0, bB0a);   // 12 pending lgkm entering loop (steady state)

    // ---- main loop: 16 iterations x 2 K-tiles ----
    #pragma unroll 1
    for (int it = 0; it < NT / 2; ++it) {
        int kt2 = ((2 * it + 2) & (NT - 1)) * BK;   // wraps at end: garbage stage, never read
        int kt3 = ((2 * it + 3) & (NT - 1)) * BK;
        TILE_BODY(0, 1, kt2, bB0a, bB0b);
        TILE_BODY(1, 0, kt3, bB0b, bB0a);
    }
    asm volatile("s_waitcnt vmcnt(0) lgkmcnt(0)" ::: "memory");   // drain wrapped garbage
    BAR();

    // ---- epilogue: dequant + bias; C/D map col=fr, row=fg*4+rr ----
    float sprod = finals[0] * finals[1];
    int orow0 = tm * BM + wm * 128 + fg * 4;
    int ocol0 = tn * BN + wn * 64 + fr;
    #pragma unroll
    for (int n = 0; n < 4; ++n) {
        int col = ocol0 + n * 16;
        float bv = bias[col];
        #pragma unroll
        for (int m = 0; m < 8; ++m) {
            int row = orow0 + m * 16;
            #pragma unroll
            for (int rr = 0; rr < 4; ++rr) {
                out[(size_t)(row + rr) * N_DIM + col] = (float)acc[m][n][rr] * sprod + bv;
            }
        }
    }
}

extern "C" void kernel_launch(void* const* d_in, const int* in_sizes, int n_in,
                              void* d_out, int out_size, void* d_ws, size_t ws_size,
                              hipStream_t stream) {
    const float* x    = (const float*)d_in[0];   // [8192, 4096]
    const float* wgt  = (const float*)d_in[1];   // [4096, 4096]
    const float* bias = (const float*)d_in[2];   // [4096]
    float* out = (float*)d_out;

    char* ws = (char*)d_ws;
    float* finals   = (float*)ws;
    float* partials = (float*)(ws + 256);
    signed char* qx = (signed char*)(ws + 16384);
    signed char* qw = qx + (size_t)M_DIM * K_DIM;

    w8a8_absmax_kernel<<<NB_TOT, 256, 0, stream>>>(x, wgt, partials);
    w8a8_quant_kernel<<<NB_TOT, 256, 0, stream>>>(x, wgt, (uint2*)qx, (uint2*)qw, partials, finals);
    w8a8_gemm_kernel<<<(M_DIM / BM) * (N_DIM / BN), 512, 0, stream>>>(qx, qw, bias, finals, out);
}

// Round 13
// 211.870 us; speedup vs baseline: 1.0096x; 1.0096x over previous
//
#include <hip/hip_runtime.h>
#include <hip/hip_bf16.h>
#include <stdint.h>

#define M_DIM 8192
#define N_DIM 4096
#define K_DIM 4096

typedef int i32x4 __attribute__((ext_vector_type(4)));

#define NB_X 2048
#define NB_W 1024
#define NB_TOT (NB_X + NB_W)

// ---------------- absmax: per-block partial max, 32B/lane, no atomics ----------------
__global__ void w8a8_absmax_kernel(const float* __restrict__ x,
                                   const float* __restrict__ w,
                                   float* __restrict__ partials) {
    int b = blockIdx.x;
    const float4* p;
    int n8, bi, nb;
    if (b < NB_X) { p = (const float4*)x; n8 = (M_DIM * K_DIM) / 8; bi = b;        nb = NB_X; }
    else          { p = (const float4*)w; n8 = (N_DIM * K_DIM) / 8; bi = b - NB_X; nb = NB_W; }

    float m = 0.f;
    int stride = nb * 256;
    for (int i = bi * 256 + threadIdx.x; i < n8; i += stride) {
        float4 v0 = p[2 * i];
        float4 v1 = p[2 * i + 1];
        float m0 = fmaxf(fmaxf(fabsf(v0.x), fabsf(v0.y)), fmaxf(fabsf(v0.z), fabsf(v0.w)));
        float m1 = fmaxf(fmaxf(fabsf(v1.x), fabsf(v1.y)), fmaxf(fabsf(v1.z), fabsf(v1.w)));
        m = fmaxf(m, fmaxf(m0, m1));
    }
    #pragma unroll
    for (int o = 32; o > 0; o >>= 1)
        m = fmaxf(m, __shfl_xor(m, o, 64));

    __shared__ float red[4];
    if ((threadIdx.x & 63) == 0) red[threadIdx.x >> 6] = m;
    __syncthreads();
    if (threadIdx.x == 0)
        partials[b] = fmaxf(fmaxf(red[0], red[1]), fmaxf(red[2], red[3]));
}

// ---------------- quantize (finalize folded in; reciprocal-mul, BW-bound) ----------------
// q = rintf(v * (1/scale)); 1/scale is ONE IEEE divide per block (deterministic, identical
// across blocks). Flip risk vs v/scale: only within ~1 ulp of a .5 boundary (~1e-7 of
// elements), each flip perturbs an output by <= s_x*s_w*127 ~= 0.24 -> negligible vs 7.28.
__global__ void w8a8_quant_kernel(const float* __restrict__ x,
                                  const float* __restrict__ w,
                                  uint2* __restrict__ qx,
                                  uint2* __restrict__ qw,
                                  const float* __restrict__ partials,
                                  float* __restrict__ finals) {
    int b = blockIdx.x;
    const float4* in4;
    uint2* outq;
    int n8, bi, nb;
    const float* pp;
    int np;
    if (b < NB_X) { in4 = (const float4*)x; outq = qx; n8 = (M_DIM * K_DIM) / 8; bi = b;        nb = NB_X; pp = partials;        np = NB_X; }
    else          { in4 = (const float4*)w; outq = qw; n8 = (N_DIM * K_DIM) / 8; bi = b - NB_X; nb = NB_W; pp = partials + NB_X; np = NB_W; }

    float m = 0.f;
    for (int i = threadIdx.x; i < np; i += 256)
        m = fmaxf(m, pp[i]);
    #pragma unroll
    for (int o = 32; o > 0; o >>= 1)
        m = fmaxf(m, __shfl_xor(m, o, 64));
    __shared__ float red[4];
    if ((threadIdx.x & 63) == 0) red[threadIdx.x >> 6] = m;
    __syncthreads();
    float am = fmaxf(fmaxf(red[0], red[1]), fmaxf(red[2], red[3]));
    float scale = fmaxf(am, 1e-5f) / 127.0f;
    float r = 1.0f / scale;                      // one IEEE divide per block
    if (threadIdx.x == 0 && (b == 0 || b == NB_X))
        finals[(b == 0) ? 0 : 1] = scale;

    int stride = nb * 256;
    for (int i = bi * 256 + threadIdx.x; i < n8; i += stride) {
        float4 v0 = in4[2 * i];
        float4 v1 = in4[2 * i + 1];
        int a0 = (int)rintf(v0.x * r), a1 = (int)rintf(v0.y * r);
        int a2 = (int)rintf(v0.z * r), a3 = (int)rintf(v0.w * r);
        int a4 = (int)rintf(v1.x * r), a5 = (int)rintf(v1.y * r);
        int a6 = (int)rintf(v1.z * r), a7 = (int)rintf(v1.w * r);
        uint2 o;
        o.x = (unsigned)(a0 & 0xff) | ((unsigned)(a1 & 0xff) << 8) |
              ((unsigned)(a2 & 0xff) << 16) | ((unsigned)(a3 & 0xff) << 24);
        o.y = (unsigned)(a4 & 0xff) | ((unsigned)(a5 & 0xff) << 8) |
              ((unsigned)(a6 & 0xff) << 16) | ((unsigned)(a7 & 0xff) << 24);
        outq[i] = o;
    }
}

// ========== 256x256 i8 GEMM (R11-proven: 131 us, structural plateau of this class) ==========
// 512 threads = 8 waves (2M x 4N). Per-wave C: 128x64 = acc[8][4] of i32x4. 16x16x64 MFMA.
// BK=128 i8. LDS: 2 x 64KB. Quadrant walk P1(0,0) P2(0,1) P3(1,1) P4(1,0); B0 persists
// in regs across the tile (ping-pong across tile parity). 4 barriers/tile.
// Drain ledger: prev-P4 OBUF reads (12) -> drained P1 LGKM(4) -> A.mh0,B.nh0 staged P2;
// B1 read P1 (4) -> drained P2 LGKM(8) -> B.nh1 staged P3; A1 read P2 (8) -> drained
// P3 LGKM(0) -> A.mh1 staged P4. vmcnt/wave: entry 8; +4 (P2) +2 (P3) = 14; VMW(6)
// end-P3 retires exactly prev tile's 8; +2 (P4) -> exit 8.
#define BM 256
#define BN 256
#define BK 128
#define NT (K_DIM / BK)      // 32 K-tiles
#define NTN (N_DIM / BN)     // 16
#define LDS_BUF 65536

#define STAGE_A(BUF, MH, KT) do {                                              \
    _Pragma("unroll")                                                          \
    for (int r_ = 0; r_ < 2; ++r_)                                             \
        __builtin_amdgcn_global_load_lds(                                      \
            (const __attribute__((address_space(1))) void*)(a_base + (size_t)((KT) + goffA[MH][r_])), \
            (__attribute__((address_space(3))) void*)(lds + (BUF)*LDS_BUF + (MH)*16384 + ldst[r_]),   \
            16, 0, 0);                                                         \
} while (0)

#define STAGE_B(BUF, NH, KT) do {                                              \
    _Pragma("unroll")                                                          \
    for (int r_ = 0; r_ < 2; ++r_)                                             \
        __builtin_amdgcn_global_load_lds(                                      \
            (const __attribute__((address_space(1))) void*)(b_base + (size_t)((KT) + goffB[NH][r_])), \
            (__attribute__((address_space(3))) void*)(lds + (BUF)*LDS_BUF + 32768 + (NH)*16384 + ldst[r_]), \
            16, 0, 0);                                                         \
} while (0)

// read A.mh frags (8 x ds_read_b128) into DST[4][2]
#define RA_A(BUF, MH, DST) do {                                                \
    _Pragma("unroll")                                                          \
    for (int m4_ = 0; m4_ < 4; ++m4_) {                                        \
        DST[m4_][0] = *(const i32x4*)(lds + (BUF)*LDS_BUF + (MH)*16384 + laneA + m4_*2048 + koff[0]); \
        DST[m4_][1] = *(const i32x4*)(lds + (BUF)*LDS_BUF + (MH)*16384 + laneA + m4_*2048 + koff[1]); \
    }                                                                          \
} while (0)

// read B.nh frags (4 x ds_read_b128) into DST[2][2]
#define RA_B(BUF, NH, DST) do {                                                \
    _Pragma("unroll")                                                          \
    for (int n1_ = 0; n1_ < 2; ++n1_) {                                        \
        DST[n1_][0] = *(const i32x4*)(lds + (BUF)*LDS_BUF + 32768 + (NH)*16384 + laneB + n1_*2048 + koff[0]); \
        DST[n1_][1] = *(const i32x4*)(lds + (BUF)*LDS_BUF + 32768 + (NH)*16384 + laneB + n1_*2048 + koff[1]); \
    }                                                                          \
} while (0)

#define MMA4(MH, NH, AARR, BARR) do {                                          \
    __builtin_amdgcn_s_setprio(1);                                             \
    _Pragma("unroll")                                                          \
    for (int m4_ = 0; m4_ < 4; ++m4_) {                                        \
        _Pragma("unroll")                                                      \
        for (int n1_ = 0; n1_ < 2; ++n1_) {                                    \
            i32x4 c_ = acc[(MH)*4 + m4_][(NH)*2 + n1_];                        \
            c_ = __builtin_amdgcn_mfma_i32_16x16x64_i8(AARR[m4_][0], BARR[n1_][0], c_, 0, 0, 0); \
            c_ = __builtin_amdgcn_mfma_i32_16x16x64_i8(AARR[m4_][1], BARR[n1_][1], c_, 0, 0, 0); \
            acc[(MH)*4 + m4_][(NH)*2 + n1_] = c_;                              \
        }                                                                      \
    }                                                                          \
    __builtin_amdgcn_s_setprio(0);                                             \
} while (0)

#define BAR() __builtin_amdgcn_s_barrier()
#define SB0() __builtin_amdgcn_sched_barrier(0)
#define VMW(N) asm volatile("s_waitcnt vmcnt(" #N ")" ::: "memory")
#define LGKM(N) asm volatile("s_waitcnt lgkmcnt(" #N ")" ::: "memory")

#define TILE_BODY(BUF, OBUF, KT2, B0C, B0N) do {                               \
    /* P1: MMA(0,0); read-ahead B1 */                                          \
    RA_B(BUF, 1, bB1);                                                         \
    SB0(); LGKM(4); SB0();          /* prev-P4's 12 OBUF-reads done */         \
    MMA4(0, 0, aA0, B0C);                                                      \
    BAR();                                                                     \
    /* P2: MMA(0,1); read-ahead A1; stage A.mh0+B.nh0 (drained P1) */          \
    STAGE_A(BUF, 0, KT2); STAGE_B(BUF, 0, KT2);                                \
    RA_A(BUF, 1, aA1);                                                         \
    SB0(); LGKM(8); SB0();          /* B1 (4 oldest) done */                   \
    MMA4(0, 1, aA0, bB1);                                                      \
    BAR();                                                                     \
    /* P3: MMA(1,1); stage B.nh1 (drained P2); merged vmcnt: OBUF stages retired */ \
    STAGE_B(BUF, 1, KT2);                                                      \
    SB0(); LGKM(0); SB0();          /* A1 done */                              \
    MMA4(1, 1, aA1, bB1);                                                      \
    SB0(); VMW(6);                  /* retire prev tile's 8 OBUF stages */     \
    BAR();                          /* all waves retired -> OBUF valid */      \
    /* P4: read-ahead next tile's A0,B0 (OBUF); stage A.mh1 (drained P3); MMA from regs */ \
    RA_A(OBUF, 0, aA0); RA_B(OBUF, 0, B0N);                                    \
    STAGE_A(BUF, 1, KT2);                                                      \
    SB0();                          /* pin read-ahead above MMA */             \
    MMA4(1, 0, aA1, B0C);                                                      \
    BAR();                                                                     \
} while (0)

__global__ __launch_bounds__(512, 1) void w8a8_gemm_kernel(
    const signed char* __restrict__ qa,   // [M, K]
    const signed char* __restrict__ qb,   // [N, K]
    const float* __restrict__ bias,       // [N]
    const float* __restrict__ finals,     // {scale_x, scale_w}
    float* __restrict__ out)              // [M, N]
{
    __shared__ __align__(16) char lds[2 * LDS_BUF];

    int t    = threadIdx.x;      // 0..511
    int lane = t & 63;
    int wid  = t >> 6;           // 0..7
    int wm   = wid >> 2;         // 0..1
    int wn   = wid & 3;          // 0..3
    int fr   = lane & 15;
    int fg   = lane >> 4;        // 0..3
    int frb2 = (fr >> 2) & 1;

    int bid = blockIdx.x;
    int cpx = gridDim.x >> 3;    // 64 (512 blocks % 8 == 0, bijective)
    int swz = (bid & 7) * cpx + (bid >> 3);
    int tm = swz / NTN;          // 0..31
    int tn = swz % NTN;          // 0..15

    const signed char* a_base = qa + (size_t)tm * BM * K_DIM;
    const signed char* b_base = qb + (size_t)tn * BN * K_DIM;

    // ---- staging precompute (per-thread constants across K) ----
    int goffA[2][2], goffB[2][2], ldst[2];
    #pragma unroll
    for (int r = 0; r < 2; ++r) {
        int unit = r * 512 + t;          // 0..1023
        int sl   = unit >> 3;            // 0..127
        int c    = unit & 7;
        int cs   = c ^ (sl & 7);         // inverse swizzle on global source
        int rowA = (sl & 63) + ((sl >> 6) & 1) * 128;
        goffA[0][r] = rowA * K_DIM + cs * 16;
        goffA[1][r] = (rowA + 64) * K_DIM + cs * 16;
        int rowB = ((sl >> 5) & 3) * 64 + (sl & 31);
        goffB[0][r] = rowB * K_DIM + cs * 16;
        goffB[1][r] = (rowB + 32) * K_DIM + cs * 16;
        ldst[r] = r * 8192 + t * 16;
    }

    // ---- read-side lane bases (swizzled) ----
    int laneA = (wm * 64 + fr) * 128 + (fg ^ (fr & 3)) * 16;
    int laneB = (wn * 32 + fr) * 128 + (fg ^ (fr & 3)) * 16;
    int koff[2];
    koff[0] = frb2 * 64;          // swizzled location of k-half 0
    koff[1] = 64 - frb2 * 64;     // swizzled location of k-half 1

    i32x4 acc[8][4] = {};
    i32x4 aA0[4][2], aA1[4][2], bB1[2][2], bB0a[2][2], bB0b[2][2];

    // ---- prologue: stage tile0 -> buf0, tile1 -> buf1; confirm buf0; preread P1 frags ----
    STAGE_A(0, 0, 0);  STAGE_A(0, 1, 0);  STAGE_B(0, 0, 0);  STAGE_B(0, 1, 0);
    STAGE_A(1, 0, BK); STAGE_A(1, 1, BK); STAGE_B(1, 0, BK); STAGE_B(1, 1, BK);
    VMW(8);            // retire tile0's 8 (own); tile1's 8 in flight
    BAR();             // all waves -> buf0 valid
    RA_A(0, 0, aA0); RA_B(0, 0, bB0a);   // 12 pending lgkm entering loop (steady state)

    // ---- main loop: 16 iterations x 2 K-tiles ----
    #pragma unroll 1
    for (int it = 0; it < NT / 2; ++it) {
        int kt2 = ((2 * it + 2) & (NT - 1)) * BK;   // wraps at end: garbage stage, never read
        int kt3 = ((2 * it + 3) & (NT - 1)) * BK;
        TILE_BODY(0, 1, kt2, bB0a, bB0b);
        TILE_BODY(1, 0, kt3, bB0b, bB0a);
    }
    asm volatile("s_waitcnt vmcnt(0) lgkmcnt(0)" ::: "memory");   // drain wrapped garbage
    BAR();

    // ---- epilogue: dequant + bias; C/D map col=fr, row=fg*4+rr ----
    float sprod = finals[0] * finals[1];
    int orow0 = tm * BM + wm * 128 + fg * 4;
    int ocol0 = tn * BN + wn * 64 + fr;
    #pragma unroll
    for (int n = 0; n < 4; ++n) {
        int col = ocol0 + n * 16;
        float bv = bias[col];
        #pragma unroll
        for (int m = 0; m < 8; ++m) {
            int row = orow0 + m * 16;
            #pragma unroll
            for (int rr = 0; rr < 4; ++rr) {
                out[(size_t)(row + rr) * N_DIM + col] = (float)acc[m][n][rr] * sprod + bv;
            }
        }
    }
}

extern "C" void kernel_launch(void* const* d_in, const int* in_sizes, int n_in,
                              void* d_out, int out_size, void* d_ws, size_t ws_size,
                              hipStream_t stream) {
    const float* x    = (const float*)d_in[0];   // [8192, 4096]
    const float* wgt  = (const float*)d_in[1];   // [4096, 4096]
    const float* bias = (const float*)d_in[2];   // [4096]
    float* out = (float*)d_out;

    char* ws = (char*)d_ws;
    float* finals   = (float*)ws;
    float* partials = (float*)(ws + 256);
    signed char* qx = (signed char*)(ws + 16384);
    signed char* qw = qx + (size_t)M_DIM * K_DIM;

    w8a8_absmax_kernel<<<NB_TOT, 256, 0, stream>>>(x, wgt, partials);
    w8a8_quant_kernel<<<NB_TOT, 256, 0, stream>>>(x, wgt, (uint2*)qx, (uint2*)qw, partials, finals);
    w8a8_gemm_kernel<<<(M_DIM / BM) * (N_DIM / BN), 512, 0, stream>>>(qx, qw, bias, finals, out);
}